// Round 3
// baseline (379.249 us; speedup 1.0000x reference)
//
#include <hip/hip_runtime.h>
#include <math.h>

// NoisyTopKRouter: x[65536,1024] fp32 -> gates[65536,8] + aux_loss.
// R6 = R5 with CHUNK 64->128: per-row HBM burst 256B->512B, column passes
// over x 16->8 (halves DRAM page revisits). R5's stagger gain (-22us) proved
// the router is HBM-pattern-limited; this attacks the remaining granularity.
// To keep 16 waves/CU: LDS held at exactly 64KB (2 bufs x 16 quads x 512
// floats, NO padding) -> 2 blocks/CU, and the block grows to 512 thr / 8
// waves (8-way k-split; each wave's FMA block shape is identical to R5's).
// Bank conflicts from the unpadded 512-stride are killed by a granule XOR
// swizzle applied on the GLOBAL SOURCE side (global_load_lds dest must stay
// lane-linear): element granule gr of quad q is stored at position
// gr ^ (q&7); compute reads apply the same XOR. Read banks:
// 4*((gr^(g&7)) mod 8) -> all 32 banks, exactly the 8-words/bank b128 floor.
// Counted vmcnt(4) + dual raw barriers (R4), stagger mod 8 (R5), wave-
// uniform scalar weights, 8-way combine, fused epilogue carried over.

#define N_TOKENS   65536
#define EMBED_DIM  1024
#define NE         8
#define BROWS      64                    // rows per block (lane = row)
#define CHUNK      128                   // k-cols per chunk
#define NCHUNK     (EMBED_DIM / CHUNK)   // 8
#define QSTRIDE    512                   // floats per 4-row quad (no pad)
#define BUFSZ      (16 * QSTRIDE)        // 8192 floats per buffer
#define NSLOT      64                    // aux accumulator spreading
#define NOISE_EPS  0.2f

#define AS1(p) (const __attribute__((address_space(1))) void*)(p)
#define AS3(p) (__attribute__((address_space(3))) void*)(p)

__global__ __launch_bounds__(512, 4)
void router_kernel(const float* __restrict__ x,
                   const float* __restrict__ eps,
                   const float* __restrict__ wg,
                   const float* __restrict__ wn,
                   float* __restrict__ gates,
                   float* __restrict__ acc /* NSLOT x 16 floats */) {
    __shared__ float tile[2][BUFSZ];     // 65536 B total; 2 blocks/CU

    const int t    = threadIdx.x;
    const int lane = t & 63;
    const int w    = __builtin_amdgcn_readfirstlane(t >> 6);   // wave 0..7
    const long rowbase = (long)blockIdx.x * BROWS;
    const int  c0 = blockIdx.x & (NCHUNK - 1);   // per-block chunk phase

    // staging map: wave w covers quads q=w*2+i (i=0,1), halves j=0,1.
    // One instr = 4 rows x 64 cols; lane -> row 4q+(lane>>4), stored granule
    // position p=lane&15 holds GLOBAL granule p^(q&7)  (source-side swizzle).
    const int srow = lane >> 4;           // 0..3
    const int pgr  = lane & 15;           // granule position 0..15

    // compute map: lane = block-row; quad g=lane>>2, row-in-quad lane&3.
    // wave w consumes k-slice [c*128 + w*16, +16): half = w>>2,
    // granule gr(j) = (w&3)*4 + j, stored at gr^(g&7).
    const int g = lane >> 2;
    const int tbase = g * QSTRIDE + (w >> 2) * 256 + (lane & 3) * 64;
    int off[4];
#pragma unroll
    for (int j = 0; j < 4; ++j)
        off[j] = ((((w & 3) * 4 + j) ^ (g & 7)) << 2);

    float accg[NE], accn[NE];
#pragma unroll
    for (int e = 0; e < NE; ++e) { accg[e] = 0.f; accn[e] = 0.f; }

    // prologue: stage logical chunks 0,1 (physical c0, c0+1) -> bufs 0,1
#pragma unroll
    for (int cc = 0; cc < 2; ++cc) {
        const int ca = (c0 + cc) & (NCHUNK - 1);
#pragma unroll
        for (int i = 0; i < 2; ++i) {
            const int q = w * 2 + i;
#pragma unroll
            for (int j = 0; j < 2; ++j) {
                const int col = ca * CHUNK + j * 64 + ((pgr ^ (q & 7)) << 2);
                const float* gp = x + (rowbase + q * 4 + srow) * (long)EMBED_DIM + col;
                __builtin_amdgcn_global_load_lds(AS1(gp),
                    AS3(&tile[cc][q * QSTRIDE + j * 256]), 16, 0, 0);
            }
        }
    }

#pragma unroll 1
    for (int c = 0; c < NCHUNK; ++c) {
        const int b  = c & 1;
        const int ca = (c0 + c) & (NCHUNK - 1);   // physical chunk this iter

        // counted wait: chunk c's own 4 loads landed; chunk c+1's 4 stay in
        // flight across the barrier (T4 — never drain mid-loop).
        if (c == NCHUNK - 1) asm volatile("s_waitcnt vmcnt(0)" ::: "memory");
        else                 asm volatile("s_waitcnt vmcnt(4)" ::: "memory");
        __builtin_amdgcn_s_barrier();          // all waves' chunk-c data in LDS
        asm volatile("" ::: "memory");         // no load hoisted above barrier

        float4 xv[4];
#pragma unroll
        for (int j = 0; j < 4; ++j)
            xv[j] = *(const float4*)&tile[b][tbase + off[j]];
        asm volatile("s_waitcnt lgkmcnt(0)" ::: "memory");  // reads retired
        __builtin_amdgcn_sched_barrier(0);
        __builtin_amdgcn_s_barrier();          // all waves done reading buf b
        asm volatile("" ::: "memory");

        // refill buf b with logical chunk c+2; lands while we FMA
        if (c + 2 < NCHUNK) {
            const int can = (c0 + c + 2) & (NCHUNK - 1);
#pragma unroll
            for (int i = 0; i < 2; ++i) {
                const int q = w * 2 + i;
#pragma unroll
                for (int j = 0; j < 2; ++j) {
                    const int col = can * CHUNK + j * 64 + ((pgr ^ (q & 7)) << 2);
                    const float* gp = x + (rowbase + q * 4 + srow) * (long)EMBED_DIM + col;
                    __builtin_amdgcn_global_load_lds(AS1(gp),
                        AS3(&tile[b][q * QSTRIDE + j * 256]), 16, 0, 0);
                }
            }
        }

        // weights are wave-uniform (ca, w scalar) -> s_load / scalar K$ path
        const float* wgc = wg + ((long)ca * CHUNK + w * 16) * NE;
        const float* wnc = wn + ((long)ca * CHUNK + w * 16) * NE;
#pragma unroll
        for (int j = 0; j < 4; ++j) {
            const float xa[4] = { xv[j].x, xv[j].y, xv[j].z, xv[j].w };
#pragma unroll
            for (int qi = 0; qi < 4; ++qi) {
                const int k = j * 4 + qi;
#pragma unroll
                for (int e = 0; e < NE; ++e) {
                    accg[e] = fmaf(xa[qi], wgc[k * NE + e], accg[e]);
                    accn[e] = fmaf(xa[qi], wnc[k * NE + e], accn[e]);
                }
            }
        }
    }

    // ---- combine 8-way k-split (scratch = 28 KB, floats 0..7167 = buf0
    // region only; last chunk (c=7) lived in buf1 -> no read/write overlap) --
    float* part = (float*)tile;
    if (w != 0) {
#pragma unroll
        for (int e = 0; e < NE; ++e) {
            part[((w - 1) * BROWS + lane) * 16 + e]      = accg[e];
            part[((w - 1) * BROWS + lane) * 16 + NE + e] = accn[e];
        }
    }
    __syncthreads();
    if (w != 0) return;

#pragma unroll
    for (int v = 0; v < 7; ++v)
#pragma unroll
        for (int e = 0; e < NE; ++e) {
            accg[e] += part[(v * BROWS + lane) * 16 + e];
            accn[e] += part[(v * BROWS + lane) * 16 + NE + e];
        }

    // ---- fused epilogue (wave 0, one row per lane) — verified in R1/R2 ----
    const long row = rowbase + lane;
    const float* er = eps + row * NE;
    float4 ev0 = *(const float4*)(er);
    float4 ev1 = *(const float4*)(er + 4);
    float epsv[NE] = { ev0.x, ev0.y, ev0.z, ev0.w, ev1.x, ev1.y, ev1.z, ev1.w };

    float noisy[NE];
#pragma unroll
    for (int e = 0; e < NE; ++e) {
        float r = accn[e];
        float sp = fmaxf(r, 0.f) + log1pf(expf(-fabsf(r)));   // stable softplus
        noisy[e] = accg[e] + (sp + NOISE_EPS) * epsv[e];
    }

    int i1 = 0; float v1 = noisy[0];
#pragma unroll
    for (int e = 1; e < NE; ++e) if (noisy[e] > v1) { v1 = noisy[e]; i1 = e; }
    int i2 = -1; float v2 = -INFINITY;
#pragma unroll
    for (int e = 0; e < NE; ++e) if (e != i1 && noisy[e] > v2) { v2 = noisy[e]; i2 = e; }

    float bb = expf(v2 - v1);
    float g2 = bb / (1.f + bb);
    float g1 = 1.f - g2;

    float* gr = gates + row * NE;
    float ov[NE];
#pragma unroll
    for (int e = 0; e < NE; ++e)
        ov[e] = (e == i1) ? g1 : ((e == i2) ? g2 : 0.f);
    *(float4*)(gr)     = make_float4(ov[0], ov[1], ov[2], ov[3]);
    *(float4*)(gr + 4) = make_float4(ov[4], ov[5], ov[6], ov[7]);

    float mx = accg[0];
#pragma unroll
    for (int e = 1; e < NE; ++e) mx = fmaxf(mx, accg[e]);
    float p[NE]; float s = 0.f;
#pragma unroll
    for (int e = 0; e < NE; ++e) { p[e] = expf(accg[e] - mx); s += p[e]; }
    float inv = 1.f / s;

    float vals[16];
#pragma unroll
    for (int e = 0; e < NE; ++e) {
        vals[e]      = p[e] * inv;
        vals[NE + e] = ((i1 == e) ? 1.f : 0.f) + ((i2 == e && g2 > 0.f) ? 1.f : 0.f);
    }
#pragma unroll
    for (int off2 = 32; off2 > 0; off2 >>= 1)
#pragma unroll
        for (int i = 0; i < 16; ++i)
            vals[i] += __shfl_xor(vals[i], off2, 64);

    if (lane == 0) {
        float* slot = acc + (blockIdx.x & (NSLOT - 1)) * 16;
#pragma unroll
        for (int i = 0; i < 16; ++i)
            atomicAdd(&slot[i], vals[i]);
    }
}

__global__ void finalize_kernel(const float* __restrict__ acc,
                                float* __restrict__ out_aux) {
    __shared__ float s[16];
    const int t = threadIdx.x;
    if (t < 16) {
        float v = 0.f;
        for (int j = 0; j < NSLOT; ++j) v += acc[j * 16 + t];
        s[t] = v;
    }
    __syncthreads();
    if (t == 0) {
        const float invn = 1.f / (float)N_TOKENS;
        float aux = 0.f;
#pragma unroll
        for (int e = 0; e < NE; ++e)
            aux += (s[e] * invn) * (s[NE + e] * invn);
        *out_aux = (float)NE * aux;
    }
}

extern "C" void kernel_launch(void* const* d_in, const int* in_sizes, int n_in,
                              void* d_out, int out_size, void* d_ws, size_t ws_size,
                              hipStream_t stream) {
    const float* x   = (const float*)d_in[0];
    const float* eps = (const float*)d_in[1];
    const float* wg  = (const float*)d_in[2];
    const float* wn  = (const float*)d_in[3];
    float* out = (float*)d_out;
    float* acc = (float*)d_ws;

    hipMemsetAsync(d_ws, 0, NSLOT * 16 * sizeof(float), stream);

    router_kernel<<<dim3(N_TOKENS / BROWS), dim3(512), 0, stream>>>(
        x, eps, wg, wn, out, acc);
    finalize_kernel<<<dim3(1), dim3(64), 0, stream>>>(acc, out + (out_size - 1));
}